// Round 2
// baseline (13.742 us; speedup 1.0000x reference)
//
#include <hip/hip_runtime.h>

#define H 1024
#define W 1024
#define N_SRC 128

// One block per image row (1024 blocks x 256 threads; thread t owns cols
// 4t..4t+3). Stages the 128 sources in LDS, zero-initializes, accumulates
// bilinear splat contributions for sources whose row-weight is nonzero
// (block-uniform test since the whole block shares one row), then does one
// coalesced float4 store. No atomics, no separate zero pass.
//
// Reference pairing: x_pos <-> ROW index, y_pos <-> COLUMN index:
//   out[h][w] = sum_n exp(lf[n]) * clip(1-|h - x_pos[n]|,0,1)
//                               * clip(1-|w - y_pos[n]|,0,1)
__global__ __launch_bounds__(256) void fused_splat_kernel(
        const float* __restrict__ log_flux,
        const float* __restrict__ x_pos,
        const float* __restrict__ y_pos,
        float4* __restrict__ out) {
    __shared__ float s_flux[N_SRC];
    __shared__ float s_x[N_SRC];
    __shared__ float s_y[N_SRC];

    int t = threadIdx.x;
    if (t < N_SRC) {
        s_flux[t] = __expf(log_flux[t]);
        s_x[t]    = x_pos[t];
        s_y[t]    = y_pos[t];
    }
    __syncthreads();

    int h = blockIdx.x;            // image row (uniform across block)
    float hf = (float)h;
    float w0 = (float)(t * 4);     // first of this thread's 4 columns

    float acc0 = 0.f, acc1 = 0.f, acc2 = 0.f, acc3 = 0.f;

    #pragma unroll 4
    for (int n = 0; n < N_SRC; ++n) {
        float wh = 1.0f - fabsf(hf - s_x[n]);   // row weight, uniform in block
        if (wh > 0.0f) {                        // block-uniform branch
            float fy = s_y[n];
            float fv = s_flux[n] * wh;
            float d0 = 1.0f - fabsf(w0         - fy);
            float d1 = 1.0f - fabsf(w0 + 1.0f  - fy);
            float d2 = 1.0f - fabsf(w0 + 2.0f  - fy);
            float d3 = 1.0f - fabsf(w0 + 3.0f  - fy);
            acc0 += fmaxf(d0, 0.0f) * fv;
            acc1 += fmaxf(d1, 0.0f) * fv;
            acc2 += fmaxf(d2, 0.0f) * fv;
            acc3 += fmaxf(d3, 0.0f) * fv;
        }
    }

    out[h * (W / 4) + t] = make_float4(acc0, acc1, acc2, acc3);
}

extern "C" void kernel_launch(void* const* d_in, const int* in_sizes, int n_in,
                              void* d_out, int out_size, void* d_ws, size_t ws_size,
                              hipStream_t stream) {
    const float* log_flux = (const float*)d_in[0];
    const float* x_pos    = (const float*)d_in[1];
    const float* y_pos    = (const float*)d_in[2];
    float4* out = (float4*)d_out;

    fused_splat_kernel<<<H, 256, 0, stream>>>(log_flux, x_pos, y_pos, out);
}

// Round 3
// 10.611 us; speedup vs baseline: 1.2950x; 1.2950x over previous
//
#include <hip/hip_runtime.h>

#define H 1024
#define W 1024
#define N_SRC 128

// One block per image row (1024 blocks x 256 threads; thread t owns cols
// 4t..4t+3). Phase 1: threads 0..127 test source t's row weight
// wh = clip(1-|h - x_pos[t]|) in parallel and compact the (rare) matches
// into an LDS list holding fv = exp(log_flux)*wh and fy = y_pos. On average
// 0.25 sources match a given row (each source spans <=2 rows). Phase 2: all
// threads loop over the compacted list (uniform count, usually 0 or 1) and
// accumulate column weights for their 4 pixels, then one coalesced float4
// store. No global atomics, no separate zero pass, no 128-iter full scan.
//
// Reference pairing: x_pos <-> ROW index, y_pos <-> COLUMN index:
//   out[h][w] = sum_n exp(lf[n]) * clip(1-|h - x_pos[n]|,0,1)
//                                * clip(1-|w - y_pos[n]|,0,1)
__global__ __launch_bounds__(256) void fused_splat_kernel(
        const float* __restrict__ log_flux,
        const float* __restrict__ x_pos,
        const float* __restrict__ y_pos,
        float4* __restrict__ out) {
    __shared__ float s_fv[N_SRC];   // exp(lf)*wh for matching sources
    __shared__ float s_fy[N_SRC];   // y (column) coordinate of matching sources
    __shared__ int   s_cnt;

    int t = threadIdx.x;
    int h = blockIdx.x;                 // image row (uniform across block)

    if (t == 0) s_cnt = 0;
    __syncthreads();

    if (t < N_SRC) {
        float wh = 1.0f - fabsf((float)h - x_pos[t]);
        if (wh > 0.0f) {
            int i = atomicAdd(&s_cnt, 1);   // LDS atomic, ~0-2 per block
            s_fv[i] = __expf(log_flux[t]) * wh;
            s_fy[i] = y_pos[t];
        }
    }
    __syncthreads();

    float w0 = (float)(t * 4);          // first of this thread's 4 columns
    float acc0 = 0.f, acc1 = 0.f, acc2 = 0.f, acc3 = 0.f;

    int cnt = s_cnt;                    // uniform
    for (int k = 0; k < cnt; ++k) {
        float fv = s_fv[k];
        float fy = s_fy[k];
        acc0 += fmaxf(1.0f - fabsf(w0         - fy), 0.0f) * fv;
        acc1 += fmaxf(1.0f - fabsf(w0 + 1.0f  - fy), 0.0f) * fv;
        acc2 += fmaxf(1.0f - fabsf(w0 + 2.0f  - fy), 0.0f) * fv;
        acc3 += fmaxf(1.0f - fabsf(w0 + 3.0f  - fy), 0.0f) * fv;
    }

    out[h * (W / 4) + t] = make_float4(acc0, acc1, acc2, acc3);
}

extern "C" void kernel_launch(void* const* d_in, const int* in_sizes, int n_in,
                              void* d_out, int out_size, void* d_ws, size_t ws_size,
                              hipStream_t stream) {
    const float* log_flux = (const float*)d_in[0];
    const float* x_pos    = (const float*)d_in[1];
    const float* y_pos    = (const float*)d_in[2];
    float4* out = (float4*)d_out;

    fused_splat_kernel<<<H, 256, 0, stream>>>(log_flux, x_pos, y_pos, out);
}

// Round 5
// 9.696 us; speedup vs baseline: 1.4173x; 1.0944x over previous
//
#include <hip/hip_runtime.h>

#define H 1024
#define W 1024
#define N_SRC 128

typedef float f32x4 __attribute__((ext_vector_type(4)));  // native vector for nontemporal store

// One block per image row (1024 blocks x 256 threads; thread t owns cols
// 4t..4t+3). Phase 1: waves 0 and 1 (threads 0..127) test source t's row
// weight wh = clip(1-|h - x_pos[t]|) and compact matches via ballot+popc
// prefix into per-wave LDS lists (no atomics, no extra barrier). On average
// only 0.25 sources match a given row. Phase 2: all threads loop over the
// two (usually empty) lists, accumulate column weights for their 4 pixels,
// and emit one coalesced nontemporal float4 store.
//
// Reference pairing: x_pos <-> ROW index, y_pos <-> COLUMN index:
//   out[h][w] = sum_n exp(lf[n]) * clip(1-|h - x_pos[n]|,0,1)
//                                * clip(1-|w - y_pos[n]|,0,1)
__global__ __launch_bounds__(256) void fused_splat_kernel(
        const float* __restrict__ log_flux,
        const float* __restrict__ x_pos,
        const float* __restrict__ y_pos,
        f32x4* __restrict__ out) {
    __shared__ float s_fv[N_SRC];   // exp(lf)*wh, per-wave regions [0..63],[64..127]
    __shared__ float s_fy[N_SRC];   // y (column) coordinate
    __shared__ int   s_cnt[2];      // per-wave match counts

    int t = threadIdx.x;
    int h = blockIdx.x;                 // image row (uniform across block)

    if (t < N_SRC) {
        int wv   = t >> 6;              // wave 0 or 1
        int lane = t & 63;
        float wh = 1.0f - fabsf((float)h - x_pos[t]);
        bool pred = wh > 0.0f;
        unsigned long long mask = __ballot(pred);
        if (pred) {
            int idx = __popcll(mask & ((1ull << lane) - 1ull));
            s_fv[wv * 64 + idx] = __expf(log_flux[t]) * wh;
            s_fy[wv * 64 + idx] = y_pos[t];
        }
        if (lane == 0) s_cnt[wv] = (int)__popcll(mask);
    }
    __syncthreads();

    float w0 = (float)(t * 4);          // first of this thread's 4 columns
    float acc0 = 0.f, acc1 = 0.f, acc2 = 0.f, acc3 = 0.f;

    int c0 = s_cnt[0];                  // uniform
    int c1 = s_cnt[1];                  // uniform
    for (int k = 0; k < c0; ++k) {
        float fv = s_fv[k], fy = s_fy[k];
        acc0 += fmaxf(1.0f - fabsf(w0         - fy), 0.0f) * fv;
        acc1 += fmaxf(1.0f - fabsf(w0 + 1.0f  - fy), 0.0f) * fv;
        acc2 += fmaxf(1.0f - fabsf(w0 + 2.0f  - fy), 0.0f) * fv;
        acc3 += fmaxf(1.0f - fabsf(w0 + 3.0f  - fy), 0.0f) * fv;
    }
    for (int k = 0; k < c1; ++k) {
        float fv = s_fv[64 + k], fy = s_fy[64 + k];
        acc0 += fmaxf(1.0f - fabsf(w0         - fy), 0.0f) * fv;
        acc1 += fmaxf(1.0f - fabsf(w0 + 1.0f  - fy), 0.0f) * fv;
        acc2 += fmaxf(1.0f - fabsf(w0 + 2.0f  - fy), 0.0f) * fv;
        acc3 += fmaxf(1.0f - fabsf(w0 + 3.0f  - fy), 0.0f) * fv;
    }

    f32x4 result = { acc0, acc1, acc2, acc3 };
    __builtin_nontemporal_store(result, &out[h * (W / 4) + t]);
}

extern "C" void kernel_launch(void* const* d_in, const int* in_sizes, int n_in,
                              void* d_out, int out_size, void* d_ws, size_t ws_size,
                              hipStream_t stream) {
    const float* log_flux = (const float*)d_in[0];
    const float* x_pos    = (const float*)d_in[1];
    const float* y_pos    = (const float*)d_in[2];
    f32x4* out = (f32x4*)d_out;

    fused_splat_kernel<<<H, 256, 0, stream>>>(log_flux, x_pos, y_pos, out);
}